// Round 13
// baseline (101.972 us; speedup 1.0000x reference)
//
#include <hip/hip_runtime.h>

#define HID 2048
#define NE 64
#define NTOK 32768        // GROUPS * TOKENS = 4 * 8192
#define CAP 160
#define GAP_THR 0.01f

typedef unsigned short u16;
typedef short bf16x8 __attribute__((ext_vector_type(8)));
typedef float f32x16 __attribute__((ext_vector_type(16)));

typedef __attribute__((address_space(1))) const void gvoid;
typedef __attribute__((address_space(3))) void lvoid;
#define GLOAD_LDS16(gp, lp) \
    __builtin_amdgcn_global_load_lds((gvoid*)(gp), (lvoid*)(lp), 16, 0, 0)

// fp32 -> bf16 hi (truncate) + bf16 lo (truncate of exact remainder).
static __device__ __forceinline__ void cvt8(const float4& a, const float4& b,
                                            bf16x8& hi, bf16x8& lo) {
    float f[8] = {a.x, a.y, a.z, a.w, b.x, b.y, b.z, b.w};
#pragma unroll
    for (int j = 0; j < 8; ++j) {
        const unsigned u = __float_as_uint(f[j]);
        const unsigned h = u >> 16;
        const float r = f[j] - __uint_as_float(h << 16);   // exact
        hi[j] = (short)h;
        lo[j] = (short)(__float_as_uint(r) >> 16);
    }
}

// ---------------------------------------------------------------------------
// K0: split W into bf16 hi/lo, fragment-major: step S (0..127) owns 4KB
// [h0|h1|l0|l1], each 1KB chunk = lane*16B.  S = global K-step = k0/16.
// ---------------------------------------------------------------------------
__global__ void k_wconv(const float* __restrict__ W, u16* __restrict__ Wfrag)
{
    const int idx = blockIdx.x * 256 + threadIdx.x;   // 0..16383
    if (idx >= NE * (HID / 8)) return;
    const int e  = idx >> 8;          // expert 0..63
    const int k0 = (idx & 255) * 8;
    const int S    = k0 >> 4;
    const int khal = (k0 >> 3) & 1;
    const int lane = (e & 31) + khal * 32;

    bf16x8 hi, lo;
    const float4 a = *(const float4*)(W + (size_t)e * HID + k0);
    const float4 b = *(const float4*)(W + (size_t)e * HID + k0 + 4);
    cvt8(a, b, hi, lo);

    u16* base = Wfrag + (size_t)S * 2048 + (size_t)(e >> 5) * 512 + lane * 8;
    *(bf16x8*)(base)        = hi;     // chunk (e>>5)
    *(bf16x8*)(base + 1024) = lo;     // chunk 2+(e>>5)
}

// ---------------------------------------------------------------------------
// K1: partial logits via 3-term bf16-split MFMA, SPLIT-K ACROSS BLOCKS.
// Block = 64 tokens x 64 experts x K-HALF (1024 k).  Grid 1024 = 4 blocks/CU
// co-resident (r12 post-mortem: per-block staging rate is ~constant, so
// throughput scales with resident blocks; r12's 1 block/CU was the bug).
// 8 waves = (ksub2, et2, tt2); each wave one 32x32 C-quadrant (acc 16 VGPR).
// Chunk = 32k: A [64tok][32f] 8KB + W 8KB, double-buffered (32KB); lacc
// 33.3KB is the LDS floor -> 4 blocks/CU, 32 waves/CU (max residency).
// Counted vmcnt(2) (2 instrs/wave/chunk, next chunk stays in flight).
// A source XOR-swizzled slot = g ^ (row&7); LDS dest linear (T2/m173).
// Output: K-half partial sums -> d_out regions (no extra ws):
//   kh=0 -> expert_out region (k_emit overwrites later), kh=1 -> logits region.
// ---------------------------------------------------------------------------
__global__ __launch_bounds__(512, 8) void k_logits(
    const float* __restrict__ A, const u16* __restrict__ Wfrag,
    float* __restrict__ P0, float* __restrict__ P1)
{
    __shared__ float smem[8320];          // stage 2x4096f (32KB); lacc 8320f
    const int tid  = threadIdx.x;
    const int lane = tid & 63;
    const int wv   = __builtin_amdgcn_readfirstlane(tid >> 6);  // 0..7
    const int ksub = wv & 1, et = (wv >> 1) & 1, tt = wv >> 2;
    const int kh   = blockIdx.x & 1;               // K-half
    const int tok0 = (blockIdx.x >> 1) * 64;

    // A DMA: wave stages rows [wv*8,+8), one 1KB instr (8 rows x 32 f).
    // lane covers row wv*8+(lane>>3), slot s=lane&7 holds granule s^(row&7).
    const int sA = lane & 7;
    const int rA = wv * 8 + (lane >> 3);
    const float* gpA = A + (size_t)(tok0 + rA) * HID + kh * 1024
                     + ((sA ^ (rA & 7)) << 2);
    // W DMA: chunk = 2 steps x 4KB contiguous; wave stages its 1KB slice.
    const u16* gpW = Wfrag + (size_t)(kh * 64) * 2048 + wv * 512 + lane * 8;

    f32x16 acc;
#pragma unroll
    for (int r = 0; r < 16; ++r) acc[r] = 0.0f;

#define MFMA_ __builtin_amdgcn_mfma_f32_32x32x16_bf16
#define DMA(C) {                                                          \
    const int b_ = (C) & 1;                                               \
    GLOAD_LDS16(gpA + (C) * 32, smem + b_ * 4096 + wv * 256);             \
    GLOAD_LDS16(gpW + (size_t)(C) * 4096,                                 \
                (u16*)(smem + b_ * 4096 + 2048) + wv * 512); }
#define COMPUTE(C) {                                                      \
    const int b_   = (C) & 1;                                             \
    const int trow = tt * 32 + (lane & 31);                               \
    const int khal = lane >> 5;                                           \
    const int g0   = ksub * 4 + khal * 2;                                 \
    const float* ab = smem + b_ * 4096 + trow * 32;                       \
    const float4 va = *(const float4*)(ab + ((g0 ^ (trow & 7)) << 2));    \
    const float4 vb = *(const float4*)(ab + (((g0 + 1) ^ (trow & 7)) << 2)); \
    const u16* wp = (const u16*)(smem + b_ * 4096 + 2048)                 \
                  + ksub * 2048 + et * 512 + lane * 8;                    \
    const bf16x8 wh = *(const bf16x8*)(wp);                               \
    const bf16x8 wl = *(const bf16x8*)(wp + 1024);                        \
    bf16x8 ah, al; cvt8(va, vb, ah, al);                                  \
    acc = MFMA_(wh, ah, acc, 0, 0, 0);                                    \
    acc = MFMA_(wl, ah, acc, 0, 0, 0);                                    \
    acc = MFMA_(wh, al, acc, 0, 0, 0); }

    // prologue: chunks 0,1 in flight (2 instrs each per wave)
    DMA(0)
    DMA(1)

#pragma unroll 1
    for (int c = 0; c < 30; ++c) {
        asm volatile("s_waitcnt vmcnt(2)" ::: "memory");   // DMA(c) landed
        __builtin_amdgcn_s_barrier();
        __builtin_amdgcn_sched_barrier(0);
        COMPUTE(c)
        __builtin_amdgcn_sched_barrier(0);
        __builtin_amdgcn_s_barrier();                      // buf c&1 free
        DMA(c + 2)
    }
    asm volatile("s_waitcnt vmcnt(2)" ::: "memory");
    __builtin_amdgcn_s_barrier();
    __builtin_amdgcn_sched_barrier(0);
    COMPUTE(30)
    asm volatile("s_waitcnt vmcnt(0)" ::: "memory");
    __builtin_amdgcn_s_barrier();
    __builtin_amdgcn_sched_barrier(0);
    COMPUTE(31)
#undef COMPUTE
#undef DMA

    __syncthreads();                      // staging done; reuse smem as lacc

    // C-quadrant -> lacc[ksub][64 tok][65]
    {
        const int trow = tt * 32 + (lane & 31);
        const int khal = lane >> 5;
        float* pl = smem + ksub * 4160 + trow * 65 + et * 32;
#pragma unroll
        for (int r = 0; r < 16; ++r) {
            const int er = (r & 3) + 8 * (r >> 2) + 4 * khal;
            pl[er] = acc[r];
        }
    }
    __syncthreads();

    // ksub-reduce, coalesced partial store (NO bias here; k_finish adds it)
    {
        const int t  = tid >> 3;          // 0..63
        const int e0 = (tid & 7) * 8;
        float v[8];
#pragma unroll
        for (int i = 0; i < 8; ++i) {
            const int o = t * 65 + e0 + i;
            v[i] = smem[o] + smem[4160 + o];
        }
        float* pp = (kh ? P1 : P0) + (size_t)(tok0 + t) * NE + e0;
        *(float4*)(pp)     = make_float4(v[0], v[1], v[2], v[3]);
        *(float4*)(pp + 4) = make_float4(v[4], v[5], v[6], v[7]);
    }
}

// ---------------------------------------------------------------------------
// K2: finish — sum K-half partials + bias -> final logits; top-2 + softmax
// denom; wave-cooperative fp64 refine of near-ties; choice + chunk histogram.
// 512 blocks x 256 thr, 64 tokens each.
// ---------------------------------------------------------------------------
__global__ __launch_bounds__(256) void k_finish(
    const float* __restrict__ P0, const float* __restrict__ P1,
    const float* __restrict__ A, const float* __restrict__ W,
    const float* __restrict__ bias,
    float* __restrict__ logits, float* __restrict__ probsmax,
    int* __restrict__ choice, int* __restrict__ cnt)
{
    __shared__ float lds[64 * 65];
    const int tid  = threadIdx.x;
    const int tok0 = blockIdx.x * 64;

    // coalesced: 1024 float4 slots; sum partials + bias, store lds + logits
#pragma unroll
    for (int i = 0; i < 4; ++i) {
        const int f4 = tid + 256 * i;     // 0..1023
        const int t  = f4 >> 4;
        const int e4 = (f4 & 15) * 4;
        const size_t go = (size_t)(tok0 + t) * NE + e4;
        const float4 a4 = *(const float4*)(P0 + go);
        const float4 b4 = *(const float4*)(P1 + go);
        float4 v;
        v.x = a4.x + b4.x + bias[e4];
        v.y = a4.y + b4.y + bias[e4 + 1];
        v.z = a4.z + b4.z + bias[e4 + 2];
        v.w = a4.w + b4.w + bias[e4 + 3];
        *(float4*)(lds + t * 65 + e4) = v;
        *(float4*)(logits + go) = v;
    }
    __syncthreads();

    if (tid < 64) {
        const int t = tid;
        float m1 = -3.4e38f, m2 = -3.4e38f;
        int i1 = 0, i2 = 0;
#pragma unroll
        for (int e = 0; e < NE; ++e) {
            const float vv = lds[t * 65 + e];
            if (vv > m1)      { m2 = m1; i2 = i1; m1 = vv; i1 = e; }
            else if (vv > m2) { m2 = vv; i2 = e; }
        }
        float sden = 0.0f;
#pragma unroll
        for (int e = 0; e < NE; ++e)
            sden += __expf(lds[t * 65 + e] - m1);
        const int g2 = tok0 + t;
        probsmax[g2] = 1.0f / sden;       // max prob = exp(0)/sum

        // wave-cooperative fp64 refine of near-ties (before counting)
        const bool flag = (m1 - m2 < GAP_THR) && (i1 != i2);
        unsigned long long msk = __ballot(flag);
        while (msk) {
            const int tt2 = (int)__ffsll((long long)msk) - 1;
            msk &= msk - 1;
            const int i1t = __shfl(i1, tt2);
            const int i2t = __shfl(i2, tt2);
            const float* a2 = A + (size_t)(tok0 + tt2) * HID;
            const float* w1 = W + (size_t)i1t * HID;
            const float* w2 = W + (size_t)i2t * HID;
            double d1 = 0.0, d2 = 0.0;
#pragma unroll 4
            for (int h = tid; h < HID; h += 64) {
                const double av = (double)a2[h];
                d1 += av * (double)w1[h];
                d2 += av * (double)w2[h];
            }
#pragma unroll
            for (int o = 32; o; o >>= 1) {
                d1 += __shfl_xor(d1, o);
                d2 += __shfl_xor(d2, o);
            }
            d1 += (double)bias[i1t];
            d2 += (double)bias[i2t];
            if (tid == tt2 && (d2 > d1 || (d2 == d1 && i2t < i1t))) i1 = i2t;
        }
        choice[g2] = i1;

        int mycnt = 0;
#pragma unroll 1
        for (int e = 0; e < NE; ++e) {
            const unsigned long long m = __ballot(i1 == e);
            if (tid == e) mycnt = (int)__popcll(m);
        }
        cnt[blockIdx.x * 64 + tid] = mycnt;
    }
}

// ---------------------------------------------------------------------------
// K3: exclusive scan of 128 chunk-histograms per group, staged in LDS.
// ---------------------------------------------------------------------------
__global__ __launch_bounds__(256) void k_scan(const int* __restrict__ cnt,
                                              int* __restrict__ off)
{
    __shared__ int sm[128 * 64];      // 32 KB
    const int tid  = threadIdx.x;
    const int base = blockIdx.x * 128 * 64;
#pragma unroll
    for (int i = 0; i < 32; ++i)
        sm[tid + 256 * i] = cnt[base + tid + 256 * i];
    __syncthreads();
    if (tid < 64) {
        int run = 0;
#pragma unroll 1
        for (int c = 0; c < 128; ++c) {
            const int idx = c * 64 + tid;
            const int v = sm[idx];
            sm[idx] = run;
            run += v;
        }
    }
    __syncthreads();
#pragma unroll
    for (int i = 0; i < 32; ++i)
        off[base + tid + 256 * i] = sm[tid + 256 * i];
}

// ---------------------------------------------------------------------------
// K4: emit expert_index rows (0/1 as fp32) with capacity mask.
// ---------------------------------------------------------------------------
__global__ void k_emit(const int* __restrict__ choice, const int* __restrict__ off,
                       float* __restrict__ eout)
{
    const int lane  = threadIdx.x & 63;
    const int wave  = threadIdx.x >> 6;
    const int chunk = blockIdx.x * 4 + wave;
    const int gt    = chunk * 64 + lane;
    const int c     = choice[gt];
    unsigned long long mymask = 0;
#pragma unroll 1
    for (int e = 0; e < NE; ++e) {
        const unsigned long long m = __ballot(c == e);
        if (c == e) mymask = m;
    }
    const int pre  = (int)__popcll(mymask & ((1ull << lane) - 1ull));
    const int base = off[chunk * 64 + c];
    const float val = (base + pre + 1 <= CAP) ? 1.0f : 0.0f;
    float* op = eout + (size_t)gt * NE;
#pragma unroll
    for (int i = 0; i < 16; ++i) {
        float4 v;
        v.x = (4*i+0 == c) ? val : 0.0f;
        v.y = (4*i+1 == c) ? val : 0.0f;
        v.z = (4*i+2 == c) ? val : 0.0f;
        v.w = (4*i+3 == c) ? val : 0.0f;
        ((float4*)op)[i] = v;
    }
}

// ---------------------------------------------------------------------------
extern "C" void kernel_launch(void* const* d_in, const int* in_sizes, int n_in,
                              void* d_out, int out_size, void* d_ws, size_t ws_size,
                              hipStream_t stream) {
    const float* A = (const float*)d_in[0];   // [4, 8192, 2048]
    const float* W = (const float*)d_in[1];   // [64, 2048]
    const float* b = (const float*)d_in[2];   // [64]

    float* out        = (float*)d_out;
    float* expert_out = out;                        // 2,097,152
    float* probsmax   = out + 2097152;              //    32,768
    float* logits     = out + 2097152 + 32768;      // 2,097,152

    // K-half partials live in d_out regions (consumed before overwritten):
    float* P0 = expert_out;   // kh=0 partial; k_emit overwrites after k_finish
    float* P1 = logits;       // kh=1 partial; k_finish sums -> final logits

    char* ws      = (char*)d_ws;
    int*   choice = (int*)(ws);                 // 128 KB
    int*   cnt    = (int*)(ws + 131072);        // 128 KB
    int*   off    = (int*)(ws + 262144);        // 128 KB
    u16*   Wfrag  = (u16*)(ws + 393216);        // 512 KB fragment-major

    hipLaunchKernelGGL(k_wconv, dim3(64), dim3(256), 0, stream, W, Wfrag);
    hipLaunchKernelGGL(k_logits, dim3(1024), dim3(512), 0, stream,
                       A, Wfrag, P0, P1);
    hipLaunchKernelGGL(k_finish, dim3(512), dim3(256), 0, stream,
                       P0, P1, A, W, b, logits, probsmax, choice, cnt);
    hipLaunchKernelGGL(k_scan, dim3(4), dim3(256), 0, stream, cnt, off);
    hipLaunchKernelGGL(k_emit, dim3(128), dim3(256), 0, stream, choice, off, expert_out);
}

// Round 14
// 97.054 us; speedup vs baseline: 1.0507x; 1.0507x over previous
//
#include <hip/hip_runtime.h>

#define HID 2048
#define NE 64
#define NTOK 32768        // GROUPS * TOKENS = 4 * 8192
#define CAP 160
#define GAP_THR 0.01f

typedef unsigned short u16;
typedef short bf16x8 __attribute__((ext_vector_type(8)));
typedef float f32x16 __attribute__((ext_vector_type(16)));

typedef __attribute__((address_space(1))) const void gvoid;
typedef __attribute__((address_space(3))) void lvoid;
#define GLOAD_LDS16(gp, lp) \
    __builtin_amdgcn_global_load_lds((gvoid*)(gp), (lvoid*)(lp), 16, 0, 0)

// fp32 -> bf16 hi (truncate) + bf16 lo (truncate of exact remainder).
static __device__ __forceinline__ void cvt8(const float4& a, const float4& b,
                                            bf16x8& hi, bf16x8& lo) {
    float f[8] = {a.x, a.y, a.z, a.w, b.x, b.y, b.z, b.w};
#pragma unroll
    for (int j = 0; j < 8; ++j) {
        const unsigned u = __float_as_uint(f[j]);
        const unsigned h = u >> 16;
        const float r = f[j] - __uint_as_float(h << 16);   // exact
        hi[j] = (short)h;
        lo[j] = (short)(__float_as_uint(r) >> 16);
    }
}

// ---------------------------------------------------------------------------
// K0: split W into bf16 hi/lo, fragment-major: step S (0..127) owns 4KB
// [h0|h1|l0|l1], each 1KB chunk = lane*16B.  S = global K-step = k0/16.
// ---------------------------------------------------------------------------
__global__ void k_wconv(const float* __restrict__ W, u16* __restrict__ Wfrag)
{
    const int idx = blockIdx.x * 256 + threadIdx.x;   // 0..16383
    if (idx >= NE * (HID / 8)) return;
    const int e  = idx >> 8;          // expert 0..63
    const int k0 = (idx & 255) * 8;
    const int S    = k0 >> 4;
    const int khal = (k0 >> 3) & 1;
    const int lane = (e & 31) + khal * 32;

    bf16x8 hi, lo;
    const float4 a = *(const float4*)(W + (size_t)e * HID + k0);
    const float4 b = *(const float4*)(W + (size_t)e * HID + k0 + 4);
    cvt8(a, b, hi, lo);

    u16* base = Wfrag + (size_t)S * 2048 + (size_t)(e >> 5) * 512 + lane * 8;
    *(bf16x8*)(base)        = hi;     // chunk (e>>5)
    *(bf16x8*)(base + 1024) = lo;     // chunk 2+(e>>5)
}

// ---------------------------------------------------------------------------
// K1: logits via 3-term bf16-split MFMA.  BARRIER-FREE K-LOOP (r13 theory:
// the invariant wall across r7-r13 was ~2.5us per barrier-iteration; compute
// per iteration is ~200cyc -> the 2 s_barriers per chunk set the clock).
// Wave = (tg, kq) = (32-token group, K-quarter of 512).  Each wave stages
// its OWN A-chunk [32 rows][32 f] (4KB) into a PRIVATE LDS double-buffer
// via global_load_lds — no cross-wave sharing, no s_barrier in the K-loop.
// W: 8 coalesced 1KB reg-loads per chunk (L2-hot), issued BEFORE DMA(c+1)
// (r8 FIFO lesson) so the compiler's W-wait = vmcnt(4) keeps A in flight;
// own-chunk wait = vmcnt(12).  Wave computes BOTH 32-expert tiles
// (acc0+acc1 = 32 VGPR).  Block = 8 waves = 2 tg x 4 kq = 64 tokens;
// K-partials LDS-reduced once at the end; finish (top-2/softmax/fp64-refine/
// count) fused in-block — no k_finish kernel, no partial traffic.
// A source XOR-swizzled slot = s ^ (row&7); LDS dest linear (T2/m173).
// ---------------------------------------------------------------------------
__global__ __launch_bounds__(512, 4) void k_logits(
    const float* __restrict__ A, const u16* __restrict__ Wfrag,
    const float* __restrict__ W, const float* __restrict__ bias,
    float* __restrict__ logits, float* __restrict__ probsmax,
    int* __restrict__ choice, int* __restrict__ cnt)
{
    __shared__ float smem[16640];   // staging 8x2048f (64KB); lacc 4x64x65
    const int tid  = threadIdx.x;
    const int lane = tid & 63;
    const int wv   = __builtin_amdgcn_readfirstlane(tid >> 6);  // 0..7
    const int tg = wv >> 2, kq = wv & 3;
    const int tok0 = blockIdx.x * 64;

    // A DMA: 4 instrs/chunk; instr i covers local rows 8i+(lane>>3) of the
    // tg; slot s=lane&7 holds granule s^(lane>>3) (row&7 == lane>>3).
    const int sgr = ((lane & 7) ^ (lane >> 3)) << 2;   // swizzled granule (floats)
    const int lr  = lane >> 3;
#define GPDEF(i) const float* gp##i = A + \
    (size_t)(tok0 + tg * 32 + 8 * (i) + lr) * HID + kq * 512 + sgr;
    GPDEF(0) GPDEF(1) GPDEF(2) GPDEF(3)
#undef GPDEF
    float* const sbase = smem + wv * 2048;   // wave-private staging (2 bufs)

    f32x16 acc0, acc1;
#pragma unroll
    for (int r = 0; r < 16; ++r) { acc0[r] = 0.0f; acc1[r] = 0.0f; }

#define MFMA_ __builtin_amdgcn_mfma_f32_32x32x16_bf16
#define DMA(C) {                                                          \
    float* d = sbase + ((C) & 1) * 1024;                                  \
    GLOAD_LDS16(gp0 + (C) * 32, d);                                       \
    GLOAD_LDS16(gp1 + (C) * 32, d + 256);                                 \
    GLOAD_LDS16(gp2 + (C) * 32, d + 512);                                 \
    GLOAD_LDS16(gp3 + (C) * 32, d + 768); }
// W(c): 8 coalesced 1KB loads (2 ks-steps x [h0|h1|l0|l1]), single-buffered.
#define LOADW(C)                                                          \
    const u16* wp0 = Wfrag + (size_t)(kq * 32 + (C) * 2) * 2048 + lane * 8; \
    const bf16x8 h0a = *(const bf16x8*)(wp0);                             \
    const bf16x8 h1a = *(const bf16x8*)(wp0 + 512);                       \
    const bf16x8 l0a = *(const bf16x8*)(wp0 + 1024);                      \
    const bf16x8 l1a = *(const bf16x8*)(wp0 + 1536);                      \
    const bf16x8 h0b = *(const bf16x8*)(wp0 + 2048);                      \
    const bf16x8 h1b = *(const bf16x8*)(wp0 + 2560);                      \
    const bf16x8 l0b = *(const bf16x8*)(wp0 + 3072);                      \
    const bf16x8 l1b = *(const bf16x8*)(wp0 + 3584);
#define COMPUTE(C) {                                                      \
    const int tr   = lane & 31;                                           \
    const int khal = lane >> 5;                                           \
    const float* ab = sbase + ((C) & 1) * 1024 + tr * 32;                 \
    {   const int g0 = khal * 2;                                          \
        const float4 va = *(const float4*)(ab + ((g0 ^ (tr & 7)) << 2));  \
        const float4 vb = *(const float4*)(ab + (((g0+1) ^ (tr & 7)) << 2)); \
        bf16x8 ah, al; cvt8(va, vb, ah, al);                              \
        acc0 = MFMA_(h0a, ah, acc0, 0, 0, 0);                             \
        acc1 = MFMA_(h1a, ah, acc1, 0, 0, 0);                             \
        acc0 = MFMA_(l0a, ah, acc0, 0, 0, 0);                             \
        acc1 = MFMA_(l1a, ah, acc1, 0, 0, 0);                             \
        acc0 = MFMA_(h0a, al, acc0, 0, 0, 0);                             \
        acc1 = MFMA_(h1a, al, acc1, 0, 0, 0);                             \
    }                                                                     \
    {   const int g0 = 4 + khal * 2;                                      \
        const float4 va = *(const float4*)(ab + ((g0 ^ (tr & 7)) << 2));  \
        const float4 vb = *(const float4*)(ab + (((g0+1) ^ (tr & 7)) << 2)); \
        bf16x8 ah, al; cvt8(va, vb, ah, al);                              \
        acc0 = MFMA_(h0b, ah, acc0, 0, 0, 0);                             \
        acc1 = MFMA_(h1b, ah, acc1, 0, 0, 0);                             \
        acc0 = MFMA_(l0b, ah, acc0, 0, 0, 0);                             \
        acc1 = MFMA_(l1b, ah, acc1, 0, 0, 0);                             \
        acc0 = MFMA_(h0b, al, acc0, 0, 0, 0);                             \
        acc1 = MFMA_(h1b, al, acc1, 0, 0, 0);                             \
    } }

    // prologue: chunk 0 in flight
    DMA(0)

#pragma unroll 1
    for (int c = 0; c < 15; ++c) {
        LOADW(c)                                      // W(c): 8 loads first
        __builtin_amdgcn_sched_barrier(0);
        DMA(c + 1)                                    // then next A chunk
        __builtin_amdgcn_sched_barrier(0);
        asm volatile("s_waitcnt vmcnt(12)" ::: "memory");  // DMA(c) landed
        __builtin_amdgcn_sched_barrier(0);
        COMPUTE(c)                                    // W-wait=vmcnt(4): A flies
    }
    {
        LOADW(15)
        __builtin_amdgcn_sched_barrier(0);
        asm volatile("s_waitcnt vmcnt(8)" ::: "memory");
        __builtin_amdgcn_sched_barrier(0);
        COMPUTE(15)
    }
#undef COMPUTE
#undef LOADW
#undef DMA

    __syncthreads();                  // FIRST barrier: staging LDS -> lacc

    // ---- C-quadrants -> lacc[kq][64 tok][65] ----
    {
        const int tr   = lane & 31;
        const int khal = lane >> 5;
        float* pl = smem + kq * 4160 + (tg * 32 + tr) * 65;
#pragma unroll
        for (int r = 0; r < 16; ++r) {
            const int er = (r & 3) + 8 * (r >> 2) + 4 * khal;
            pl[er]      = acc0[r];
            pl[32 + er] = acc1[r];
        }
    }
    __syncthreads();

    // split-K reduce (+bias), coalesced logits store, stash row into plane 0
    {
        const int t  = tid >> 3;          // 0..63
        const int e0 = (tid & 7) * 8;
        float v[8];
#pragma unroll
        for (int i = 0; i < 8; ++i) {
            const int o = t * 65 + e0 + i;
            v[i] = smem[o] + smem[4160 + o] + smem[8320 + o] + smem[12480 + o]
                 + bias[e0 + i];
        }
        float* lp = logits + (size_t)(tok0 + t) * NE + e0;
        *(float4*)(lp)     = make_float4(v[0], v[1], v[2], v[3]);
        *(float4*)(lp + 4) = make_float4(v[4], v[5], v[6], v[7]);
#pragma unroll
        for (int i = 0; i < 8; ++i) smem[t * 65 + e0 + i] = v[i];
    }
    __syncthreads();

    // per-token epilogue (wave 0): top-2 + softmax denom -> fp64 refine of
    // near-ties (wave-cooperative) -> choice + fused chunk histogram.
    if (tid < 64) {
        const int t = tid;
        float m1 = -3.4e38f, m2 = -3.4e38f;
        int i1 = 0, i2 = 0;
#pragma unroll
        for (int e = 0; e < NE; ++e) {
            const float vv = smem[t * 65 + e];
            if (vv > m1)      { m2 = m1; i2 = i1; m1 = vv; i1 = e; }
            else if (vv > m2) { m2 = vv; i2 = e; }
        }
        float sden = 0.0f;
#pragma unroll
        for (int e = 0; e < NE; ++e)
            sden += __expf(smem[t * 65 + e] - m1);
        const int g2 = tok0 + t;
        probsmax[g2] = 1.0f / sden;       // max prob = exp(0)/sum

        const bool flag = (m1 - m2 < GAP_THR) && (i1 != i2);
        unsigned long long msk = __ballot(flag);
        while (msk) {
            const int tt2 = (int)__ffsll((long long)msk) - 1;
            msk &= msk - 1;
            const int i1t = __shfl(i1, tt2);
            const int i2t = __shfl(i2, tt2);
            const float* a2 = A + (size_t)(tok0 + tt2) * HID;
            const float* w1 = W + (size_t)i1t * HID;
            const float* w2 = W + (size_t)i2t * HID;
            double d1 = 0.0, d2 = 0.0;
#pragma unroll 4
            for (int h = tid; h < HID; h += 64) {
                const double av = (double)a2[h];
                d1 += av * (double)w1[h];
                d2 += av * (double)w2[h];
            }
#pragma unroll
            for (int o = 32; o; o >>= 1) {
                d1 += __shfl_xor(d1, o);
                d2 += __shfl_xor(d2, o);
            }
            d1 += (double)bias[i1t];
            d2 += (double)bias[i2t];
            if (tid == tt2 && (d2 > d1 || (d2 == d1 && i2t < i1t))) i1 = i2t;
        }
        choice[g2] = i1;

        int mycnt = 0;
#pragma unroll 1
        for (int e = 0; e < NE; ++e) {
            const unsigned long long m = __ballot(i1 == e);
            if (tid == e) mycnt = (int)__popcll(m);
        }
        cnt[blockIdx.x * 64 + tid] = mycnt;
    }
}

// ---------------------------------------------------------------------------
// K3: exclusive scan of 128 chunk-histograms per group, staged in LDS.
// ---------------------------------------------------------------------------
__global__ __launch_bounds__(256) void k_scan(const int* __restrict__ cnt,
                                              int* __restrict__ off)
{
    __shared__ int sm[128 * 64];      // 32 KB
    const int tid  = threadIdx.x;
    const int base = blockIdx.x * 128 * 64;
#pragma unroll
    for (int i = 0; i < 32; ++i)
        sm[tid + 256 * i] = cnt[base + tid + 256 * i];
    __syncthreads();
    if (tid < 64) {
        int run = 0;
#pragma unroll 1
        for (int c = 0; c < 128; ++c) {
            const int idx = c * 64 + tid;
            const int v = sm[idx];
            sm[idx] = run;
            run += v;
        }
    }
    __syncthreads();
#pragma unroll
    for (int i = 0; i < 32; ++i)
        off[base + tid + 256 * i] = sm[tid + 256 * i];
}

// ---------------------------------------------------------------------------
// K4: emit expert_index rows (0/1 as fp32) with capacity mask.
// ---------------------------------------------------------------------------
__global__ void k_emit(const int* __restrict__ choice, const int* __restrict__ off,
                       float* __restrict__ eout)
{
    const int lane  = threadIdx.x & 63;
    const int wave  = threadIdx.x >> 6;
    const int chunk = blockIdx.x * 4 + wave;
    const int gt    = chunk * 64 + lane;
    const int c     = choice[gt];
    unsigned long long mymask = 0;
#pragma unroll 1
    for (int e = 0; e < NE; ++e) {
        const unsigned long long m = __ballot(c == e);
        if (c == e) mymask = m;
    }
    const int pre  = (int)__popcll(mymask & ((1ull << lane) - 1ull));
    const int base = off[chunk * 64 + c];
    const float val = (base + pre + 1 <= CAP) ? 1.0f : 0.0f;
    float* op = eout + (size_t)gt * NE;
#pragma unroll
    for (int i = 0; i < 16; ++i) {
        float4 v;
        v.x = (4*i+0 == c) ? val : 0.0f;
        v.y = (4*i+1 == c) ? val : 0.0f;
        v.z = (4*i+2 == c) ? val : 0.0f;
        v.w = (4*i+3 == c) ? val : 0.0f;
        ((float4*)op)[i] = v;
    }
}

// ---------------------------------------------------------------------------
extern "C" void kernel_launch(void* const* d_in, const int* in_sizes, int n_in,
                              void* d_out, int out_size, void* d_ws, size_t ws_size,
                              hipStream_t stream) {
    const float* A = (const float*)d_in[0];   // [4, 8192, 2048]
    const float* W = (const float*)d_in[1];   // [64, 2048]
    const float* b = (const float*)d_in[2];   // [64]

    float* out        = (float*)d_out;
    float* expert_out = out;                        // 2,097,152
    float* probsmax   = out + 2097152;              //    32,768
    float* logits     = out + 2097152 + 32768;      // 2,097,152

    char* ws      = (char*)d_ws;
    int*   choice = (int*)(ws);                 // 128 KB
    int*   cnt    = (int*)(ws + 131072);        // 128 KB
    int*   off    = (int*)(ws + 262144);        // 128 KB
    u16*   Wfrag  = (u16*)(ws + 393216);        // 512 KB fragment-major

    hipLaunchKernelGGL(k_wconv, dim3(64), dim3(256), 0, stream, W, Wfrag);
    hipLaunchKernelGGL(k_logits, dim3(512), dim3(512), 0, stream,
                       A, Wfrag, W, b, logits, probsmax, choice, cnt);
    hipLaunchKernelGGL(k_scan, dim3(4), dim3(256), 0, stream, cnt, off);
    hipLaunchKernelGGL(k_emit, dim3(128), dim3(256), 0, stream, choice, off, expert_out);
}